// Round 15
// baseline (464.984 us; speedup 1.0000x reference)
//
#include <hip/hip_runtime.h>
#include <math.h>

#define N_NODES 50000
#define N_EDGES 800000
#define HC 64
#define HID 16
#define EDIM 16
#define NGRAPH 2000
#define BN_EPS 1e-5f
#define QKVS_NODES 32
#define XSP 68   // xs row stride (floats): 68%4==0 (16B align), 68%32==4 -> 4 consecutive rows hit disjoint bank quads
#define SCAN_NBLK ((N_NODES + 255) / 256)   // 196
#define SCAT_BLOCKS 2048                    // multiple of 8 (XCD classes); latency-bound -> big grid
#define NODES_PER_CLS (N_NODES / 8)         // 6250

// ---- fp8 e4m3 (OCP) helpers: HW cvt on gfx950 ----
typedef __attribute__((ext_vector_type(2))) float v2f;
typedef __attribute__((ext_vector_type(4))) float v4f;   // native vec type (nontemporal-load compatible)
__device__ inline float4 fp8x4_to_f4(unsigned w) {
    v2f lo = __builtin_amdgcn_cvt_pk_f32_fp8((int)w, false);
    v2f hi = __builtin_amdgcn_cvt_pk_f32_fp8((int)w, true);
    return make_float4(lo[0], lo[1], hi[0], hi[1]);
}
__device__ inline unsigned char f2fp8(float f) {
    int r = __builtin_amdgcn_cvt_pk_fp8_f32(f, f, 0, false);
    return (unsigned char)(r & 0xff);
}
// ---- bf16 helpers: RNE pack, shift-expand ----
__device__ inline unsigned short f2bf(float f) {
    union { float f; unsigned u; } v; v.f = f;
    unsigned r = v.u + 0x7fffu + ((v.u >> 16) & 1u);
    return (unsigned short)(r >> 16);
}
__device__ inline unsigned pk2bf(float a, float b) {
    return (unsigned)f2bf(a) | ((unsigned)f2bf(b) << 16);
}
__device__ inline float4 bf4_to_f4(uint2 r) {
    float4 o;
    o.x = __uint_as_float(r.x << 16);
    o.y = __uint_as_float(r.x & 0xffff0000u);
    o.z = __uint_as_float(r.y << 16);
    o.w = __uint_as_float(r.y & 0xffff0000u);
    return o;
}

// ---------- CSR build ----------
__global__ void count_deg(const int* __restrict__ ei, int* __restrict__ deg) {
    int e = blockIdx.x * blockDim.x + threadIdx.x;
    if (e < N_EDGES) atomicAdd(&deg[ei[N_EDGES + e]], 1);
}

__global__ __launch_bounds__(256) void scan1(const int* __restrict__ deg, int* __restrict__ bsum) {
    __shared__ int s[256];
    int tid = threadIdx.x;
    int i = blockIdx.x * 256 + tid;
    s[tid] = (i < N_NODES) ? deg[i] : 0;
    __syncthreads();
    for (int d = 128; d > 0; d >>= 1) {
        if (tid < d) s[tid] += s[tid + d];
        __syncthreads();
    }
    if (tid == 0) bsum[blockIdx.x] = s[0];
}

// scan3 folds scan2: every block redundantly prefix-scans the 196 block sums
// in LDS to derive its own exclusive block offset — one fewer dispatch.
__global__ __launch_bounds__(256) void scan3(const int* __restrict__ deg, const int* __restrict__ bsum,
                                             int* __restrict__ row_ptr, int* __restrict__ nxt) {
    __shared__ int s[256];
    __shared__ int boff_s;
    int tid = threadIdx.x;
    int v2 = (tid < SCAN_NBLK) ? bsum[tid] : 0;
    s[tid] = v2;
    __syncthreads();
    for (int d = 1; d < 256; d <<= 1) {
        int t = (tid >= d) ? s[tid - d] : 0;
        __syncthreads();
        s[tid] += t;
        __syncthreads();
    }
    if (tid == (int)blockIdx.x) boff_s = s[tid] - v2;   // exclusive prefix for this block
    __syncthreads();
    int i = blockIdx.x * 256 + tid;
    int v = (i < N_NODES) ? deg[i] : 0;
    s[tid] = v;
    __syncthreads();
    for (int d = 1; d < 256; d <<= 1) {
        int t = (tid >= d) ? s[tid - d] : 0;
        __syncthreads();
        s[tid] += t;
        __syncthreads();
    }
    int excl = s[tid] - v + boff_s;
    if (i < N_NODES) { row_ptr[i] = excl; nxt[i] = excl; }
    if (i == 0) row_ptr[N_NODES] = N_EDGES;
}

// XCD-class-partitioned scatter (R11) + CSR-ordered bf16 edge_attr copy (R13)
// + R14: ALL streaming reads nontemporal so the 51.2MB edge_attr gather does
// not evict the class's ~3.2MB ea_s write window from its XCD L2 (that
// eviction caused 2.4x write amplification), and 2x grid for gather MLP.
__global__ __launch_bounds__(256) void scatter_edges(const int* __restrict__ ei,
                                                     const float* __restrict__ edge_attr,
                                                     int* __restrict__ next_ptr,
                                                     int* __restrict__ src_s,
                                                     unsigned short* __restrict__ ea_s) {
    int cls = blockIdx.x & 7;
    int nodeLo = cls * NODES_PER_CLS;
    int nodeHi = nodeLo + NODES_PER_CLS;
    int stride = (SCAT_BLOCKS >> 3) * 256;
    int e = (blockIdx.x >> 3) * 256 + threadIdx.x;
    for (; e < N_EDGES; e += stride) {
        int d = __builtin_nontemporal_load(ei + N_EDGES + e);
        if (d >= nodeLo && d < nodeHi) {
            int s = __builtin_nontemporal_load(ei + e);
            int p = atomicAdd(&next_ptr[d], 1);
            src_s[p] = s;
            const v4f* a = (const v4f*)(edge_attr + (size_t)e * EDIM);
            v4f a0 = __builtin_nontemporal_load(a + 0);
            v4f a1 = __builtin_nontemporal_load(a + 1);
            v4f a2 = __builtin_nontemporal_load(a + 2);
            v4f a3 = __builtin_nontemporal_load(a + 3);
            uint4 w0, w1;
            w0.x = pk2bf(a0[0], a0[1]); w0.y = pk2bf(a0[2], a0[3]);
            w0.z = pk2bf(a1[0], a1[1]); w0.w = pk2bf(a1[2], a1[3]);
            w1.x = pk2bf(a2[0], a2[1]); w1.y = pk2bf(a2[2], a2[3]);
            w1.z = pk2bf(a3[0], a3[1]); w1.w = pk2bf(a3[2], a3[3]);
            uint4* dst = (uint4*)(ea_s + (size_t)p * EDIM);
            dst[0] = w0; dst[1] = w1;
        }
    }
}

// ---------- fused Q/K/V/Skip GEMM + qWe phase (R7 tiling) ----------
// Outputs: K/V fp8 (128B/node row, split K|V), Q/S/qWe bf16.
__global__ __launch_bounds__(256) void qkvs_kernel(
    const float* __restrict__ x,
    const float* __restrict__ Wq, const float* __restrict__ bq,
    const float* __restrict__ Wk, const float* __restrict__ bk,
    const float* __restrict__ Wv, const float* __restrict__ bv,
    const float* __restrict__ Ws, const float* __restrict__ bs,
    const float* __restrict__ We,
    unsigned short* __restrict__ Qo, unsigned char* __restrict__ KVo,
    unsigned short* __restrict__ So, unsigned short* __restrict__ qwe_buf) {
    __shared__ float xs[QKVS_NODES][XSP];
    int tid = threadIdx.x;
    int n0 = blockIdx.x * QKVS_NODES;
    for (int c = tid; c < QKVS_NODES * HC / 4; c += 256) {
        int row = c >> 4, col4 = c & 15;
        int n = n0 + row;
        float4 v = (n < N_NODES) ? ((const float4*)(x + (size_t)n * HC))[col4]
                                 : make_float4(0.f, 0.f, 0.f, 0.f);
        *(float4*)&xs[row][col4 * 4] = v;
    }
    __syncthreads();
    int sel = tid >> 6;
    int t = tid & 63;
    int j4 = (t & 15) * 4;        // column base (0,4,...,60)
    int ng = t >> 4;              // node sub-lane 0..3; thread's nodes: ng + 4*i
    const float* W; const float* B;
    if (sel == 0)      { W = Wq; B = bq; }
    else if (sel == 1) { W = Wk; B = bk; }
    else if (sel == 2) { W = Wv; B = bv; }
    else               { W = Ws; B = bs; }
    float4 b4 = *(const float4*)(B + j4);
    float acc[8][4];
#pragma unroll
    for (int n = 0; n < 8; n++) {
        acc[n][0] = b4.x; acc[n][1] = b4.y; acc[n][2] = b4.z; acc[n][3] = b4.w;
    }
    for (int i4 = 0; i4 < HC / 4; i4++) {
        float4 w0 = *(const float4*)(W + (i4 * 4 + 0) * HC + j4);
        float4 w1 = *(const float4*)(W + (i4 * 4 + 1) * HC + j4);
        float4 w2 = *(const float4*)(W + (i4 * 4 + 2) * HC + j4);
        float4 w3 = *(const float4*)(W + (i4 * 4 + 3) * HC + j4);
#pragma unroll
        for (int n = 0; n < 8; n++) {
            float4 xv = *(const float4*)&xs[ng + 4 * n][i4 * 4];
            acc[n][0] = fmaf(xv.x, w0.x, acc[n][0]);
            acc[n][0] = fmaf(xv.y, w1.x, acc[n][0]);
            acc[n][0] = fmaf(xv.z, w2.x, acc[n][0]);
            acc[n][0] = fmaf(xv.w, w3.x, acc[n][0]);
            acc[n][1] = fmaf(xv.x, w0.y, acc[n][1]);
            acc[n][1] = fmaf(xv.y, w1.y, acc[n][1]);
            acc[n][1] = fmaf(xv.z, w2.y, acc[n][1]);
            acc[n][1] = fmaf(xv.w, w3.y, acc[n][1]);
            acc[n][2] = fmaf(xv.x, w0.z, acc[n][2]);
            acc[n][2] = fmaf(xv.y, w1.z, acc[n][2]);
            acc[n][2] = fmaf(xv.z, w2.z, acc[n][2]);
            acc[n][2] = fmaf(xv.w, w3.z, acc[n][2]);
            acc[n][3] = fmaf(xv.x, w0.w, acc[n][3]);
            acc[n][3] = fmaf(xv.y, w1.w, acc[n][3]);
            acc[n][3] = fmaf(xv.z, w2.w, acc[n][3]);
            acc[n][3] = fmaf(xv.w, w3.w, acc[n][3]);
        }
    }
    if (sel == 0 || sel == 3) {
        unsigned short* Out = (sel == 0) ? Qo : So;
#pragma unroll
        for (int n = 0; n < 8; n++) {
            int node = n0 + ng + 4 * n;
            if (node < N_NODES) {
                ushort4 pk;
                pk.x = f2bf(acc[n][0]); pk.y = f2bf(acc[n][1]);
                pk.z = f2bf(acc[n][2]); pk.w = f2bf(acc[n][3]);
                *(ushort4*)(Out + (size_t)node * HC + j4) = pk;
            }
        }
    } else {
        int off = (sel == 1) ? 0 : HC;
#pragma unroll
        for (int n = 0; n < 8; n++) {
            int node = n0 + ng + 4 * n;
            if (node < N_NODES) {
                uchar4 pk;
                pk.x = f2fp8(acc[n][0]); pk.y = f2fp8(acc[n][1]);
                pk.z = f2fp8(acc[n][2]); pk.w = f2fp8(acc[n][3]);
                *(uchar4*)(KVo + (size_t)node * 2 * HC + off + j4) = pk;
            }
        }
    }

    // ---- phase 2: qWe[node][h*16+jj] = sum_d Q[node][h*16+d] * We[jj][h*16+d] ----
    __syncthreads();                 // xs no longer needed for x
    if (sel == 0) {
#pragma unroll
        for (int n = 0; n < 8; n++)  // Q tile (fp32) -> LDS
            *(float4*)&xs[ng + 4 * n][j4] =
                make_float4(acc[n][0], acc[n][1], acc[n][2], acc[n][3]);
    }
    __syncthreads();
    {
        int j = tid & 63;
        int h2 = j >> 4, jj = j & 15;
        float4 wv0 = *(const float4*)(We + jj * HC + h2 * 16 + 0);
        float4 wv1 = *(const float4*)(We + jj * HC + h2 * 16 + 4);
        float4 wv2 = *(const float4*)(We + jj * HC + h2 * 16 + 8);
        float4 wv3 = *(const float4*)(We + jj * HC + h2 * 16 + 12);
#pragma unroll
        for (int n = 0; n < 8; n++) {
            int nn = sel * 8 + n;
            float4 q0 = *(const float4*)&xs[nn][h2 * 16 + 0];
            float4 q1 = *(const float4*)&xs[nn][h2 * 16 + 4];
            float4 q2 = *(const float4*)&xs[nn][h2 * 16 + 8];
            float4 q3 = *(const float4*)&xs[nn][h2 * 16 + 12];
            float s = q0.x * wv0.x + q0.y * wv0.y + q0.z * wv0.z + q0.w * wv0.w
                    + q1.x * wv1.x + q1.y * wv1.y + q1.z * wv1.z + q1.w * wv1.w
                    + q2.x * wv2.x + q2.y * wv2.y + q2.z * wv2.z + q2.w * wv2.w
                    + q3.x * wv3.x + q3.y * wv3.y + q3.z * wv3.z + q3.w * wv3.w;
            int node = n0 + nn;
            if (node < N_NODES) qwe_buf[(size_t)node * HC + j] = f2bf(s);
        }
    }
}

// ---------- attention + skip + BN + ReLU (fp8 KV, bf16 Q/Qwe/S, bf16 CSR-ordered ea) ----------
__global__ __launch_bounds__(256) void attn_kernel(
    const unsigned short* __restrict__ Qf, const unsigned short* __restrict__ Qwe,
    const unsigned char* __restrict__ KV, const unsigned short* __restrict__ Sf,
    const int* __restrict__ row_ptr, const int* __restrict__ src_s,
    const unsigned short* __restrict__ ea_s, const float* __restrict__ We,
    const float* __restrict__ bng, const float* __restrict__ bnb,
    const float* __restrict__ bnm, const float* __restrict__ bnv,
    float* __restrict__ x_out) {
    __shared__ float we_s[EDIM * HC];  // 4 KB
    int tid = threadIdx.x;
    for (int c = tid; c < EDIM * HC / 4; c += 256)
        ((float4*)we_s)[c] = ((const float4*)We)[c];
    __syncthreads();

    int lane = tid & 63;
    int wave = tid >> 6;
    int half = lane >> 5;                       // which node of the wave's pair
    int node = blockIdx.x * 8 + wave * 2 + half;  // 6250 blocks * 8 = 50000 exactly
    int sub = (lane >> 4) & 1;                  // 2 edge-streams per node
    int pos = lane & 15;
    int h = pos >> 2;
    int eaIdx = pos & 3;
    int rbeg = row_ptr[node], rend = row_ptr[node + 1];

    float4 q4 = bf4_to_f4(((const uint2*)(Qf + (size_t)node * HC))[pos]);
    float4 qwe = bf4_to_f4(((const uint2*)(Qwe + (size_t)node * HC))[pos]);  // qWe[h][jbase..+3]

    float den = 0.f;
    float4 acc = make_float4(0.f, 0.f, 0.f, 0.f);   // sum p * v
    float4 aea = make_float4(0.f, 0.f, 0.f, 0.f);   // sum p * ea

    auto proc = [&](float4 k4, float4 ea4) -> float {
        float dot = q4.x * k4.x + q4.y * k4.y + q4.z * k4.z + q4.w * k4.w
                  + qwe.x * ea4.x + qwe.y * ea4.y + qwe.z * ea4.z + qwe.w * ea4.w;
        dot += __shfl_xor(dot, 1);
        dot += __shfl_xor(dot, 2);
        float p = __expf(dot * 0.25f);
        den += p;
        return p;
    };
    auto accum = [&](float p, const float4& v, const float4& ea) {
        acc.x = fmaf(p, v.x, acc.x); acc.y = fmaf(p, v.y, acc.y);
        acc.z = fmaf(p, v.z, acc.z); acc.w = fmaf(p, v.w, acc.w);
        aea.x = fmaf(p, ea.x, aea.x); aea.y = fmaf(p, ea.y, aea.y);
        aea.z = fmaf(p, ea.z, aea.z); aea.w = fmaf(p, ea.w, aea.w);
    };

    int j = rbeg + sub;
    for (; j + 2 < rend; j += 4) {
        int s0 = src_s[j];
        int s1 = src_s[j + 2];
        const unsigned int* kv0 = (const unsigned int*)(KV + (size_t)s0 * 2 * HC);
        const unsigned int* kv1 = (const unsigned int*)(KV + (size_t)s1 * 2 * HC);
        unsigned int k0w = kv0[pos], v0w = kv0[16 + pos];
        unsigned int k1w = kv1[pos], v1w = kv1[16 + pos];
        float4 ea0 = bf4_to_f4(((const uint2*)(ea_s + (size_t)j * EDIM))[eaIdx]);
        float4 ea1 = bf4_to_f4(((const uint2*)(ea_s + (size_t)(j + 2) * EDIM))[eaIdx]);
        float4 k0 = fp8x4_to_f4(k0w), v0 = fp8x4_to_f4(v0w);
        float4 k1 = fp8x4_to_f4(k1w), v1 = fp8x4_to_f4(v1w);
        float p0 = proc(k0, ea0);
        accum(p0, v0, ea0);
        float p1 = proc(k1, ea1);
        accum(p1, v1, ea1);
    }
    if (j < rend) {
        int s0 = src_s[j];
        const unsigned int* kv0 = (const unsigned int*)(KV + (size_t)s0 * 2 * HC);
        unsigned int k0w = kv0[pos], v0w = kv0[16 + pos];
        float4 ea0 = bf4_to_f4(((const uint2*)(ea_s + (size_t)j * EDIM))[eaIdx]);
        float4 k0 = fp8x4_to_f4(k0w), v0 = fp8x4_to_f4(v0w);
        float p0 = proc(k0, ea0);
        accum(p0, v0, ea0);
    }

    // merge the 2 sub-stream partial sums (within the 32-lane half) — plain adds
    {
        den += __shfl_xor(den, 16);
        acc.x += __shfl_xor(acc.x, 16); acc.y += __shfl_xor(acc.y, 16);
        acc.z += __shfl_xor(acc.z, 16); acc.w += __shfl_xor(acc.w, 16);
        aea.x += __shfl_xor(aea.x, 16); aea.y += __shfl_xor(aea.y, 16);
        aea.z += __shfl_xor(aea.z, 16); aea.w += __shfl_xor(aea.w, 16);
    }

    // epilogue: e_contrib[pos*4+c] = sum_j aggEA[h][j] * We[j][pos*4+c]
    float4 e4 = make_float4(0.f, 0.f, 0.f, 0.f);
#pragma unroll
    for (int jg = 0; jg < 4; jg++) {
        int sl = (lane & 32) | (h * 4 + jg);  // lane in this half holding aggEA[h][jg*4..+3]
        float a0 = __shfl(aea.x, sl), a1 = __shfl(aea.y, sl);
        float a2 = __shfl(aea.z, sl), a3 = __shfl(aea.w, sl);
        float4 w0 = *(const float4*)(we_s + (jg * 4 + 0) * HC + pos * 4);
        float4 w1 = *(const float4*)(we_s + (jg * 4 + 1) * HC + pos * 4);
        float4 w2 = *(const float4*)(we_s + (jg * 4 + 2) * HC + pos * 4);
        float4 w3 = *(const float4*)(we_s + (jg * 4 + 3) * HC + pos * 4);
        e4.x += a0 * w0.x + a1 * w1.x + a2 * w2.x + a3 * w3.x;
        e4.y += a0 * w0.y + a1 * w1.y + a2 * w2.y + a3 * w3.y;
        e4.z += a0 * w0.z + a1 * w1.z + a2 * w2.z + a3 * w3.z;
        e4.w += a0 * w0.w + a1 * w1.w + a2 * w2.w + a3 * w3.w;
    }

    float inv = (rend > rbeg) ? 1.f / den : 0.f;
    float4 sk = bf4_to_f4(((const uint2*)(Sf + (size_t)node * HC))[pos]);
    float4 o = make_float4((acc.x + e4.x) * inv + sk.x, (acc.y + e4.y) * inv + sk.y,
                           (acc.z + e4.z) * inv + sk.z, (acc.w + e4.w) * inv + sk.w);
    float4 g4 = ((const float4*)bng)[pos];
    float4 b4 = ((const float4*)bnb)[pos];
    float4 m4 = ((const float4*)bnm)[pos];
    float4 vv4 = ((const float4*)bnv)[pos];
    o.x = fmaxf((o.x - m4.x) * rsqrtf(vv4.x + BN_EPS) * g4.x + b4.x, 0.f);
    o.y = fmaxf((o.y - m4.y) * rsqrtf(vv4.y + BN_EPS) * g4.y + b4.y, 0.f);
    o.z = fmaxf((o.z - m4.z) * rsqrtf(vv4.z + BN_EPS) * g4.z + b4.z, 0.f);
    o.w = fmaxf((o.w - m4.w) * rsqrtf(vv4.w + BN_EPS) * g4.w + b4.w, 0.f);
    if (sub == 0) ((float4*)(x_out + (size_t)node * HC))[pos] = o;
}

// ---------- fused mean-pool + MLP head: one wave per graph ----------
__global__ __launch_bounds__(256) void pool_head(
    const float* __restrict__ x, const int* __restrict__ batch,
    const float* __restrict__ fc1_w, const float* __restrict__ fc1_b,
    const float* __restrict__ fc2_w, const float* __restrict__ fc2_b,
    float* __restrict__ out) {
    __shared__ float ps[4][HC];
    int q = threadIdx.x >> 6;
    int lane = threadIdx.x & 63;
    int g = blockIdx.x * 4 + q;           // 500 * 4 = 2000 exactly
    int lo = 0, hi = N_NODES;
    while (lo < hi) { int mid = (lo + hi) >> 1; if (batch[mid] < g) lo = mid + 1; else hi = mid; }
    int beg = lo;
    lo = 0; hi = N_NODES;
    while (lo < hi) { int mid = (lo + hi) >> 1; if (batch[mid] < g + 1) lo = mid + 1; else hi = mid; }
    int end = lo;
    float s = 0.f;
    for (int i = beg; i < end; i++) s += x[(size_t)i * HC + lane];  // coalesced
    float inv = (end > beg) ? 1.f / (float)(end - beg) : 1.f;
    ps[q][lane] = s * inv;
    __syncthreads();
    float o = 0.f;
    if (lane < HID) {
        float a = fc1_b[lane];
#pragma unroll
        for (int i = 0; i < HC; i++) a = fmaf(ps[q][i], fc1_w[i * HID + lane], a);
        o = fmaxf(a, 0.f) * fc2_w[lane];
    }
    o += __shfl_xor(o, 1);
    o += __shfl_xor(o, 2);
    o += __shfl_xor(o, 4);
    o += __shfl_xor(o, 8);
    if (lane == 0) out[g] = o + fc2_b[0];
}

extern "C" void kernel_launch(void* const* d_in, const int* in_sizes, int n_in,
                              void* d_out, int out_size, void* d_ws, size_t ws_size,
                              hipStream_t stream) {
    const float* x         = (const float*)d_in[0];
    const int*   ei        = (const int*)d_in[1];
    const float* edge_attr = (const float*)d_in[2];
    const int*   batch     = (const int*)d_in[3];
    const float* Wq = (const float*)d_in[4];  const float* bq = (const float*)d_in[5];
    const float* Wk = (const float*)d_in[6];  const float* bk = (const float*)d_in[7];
    const float* Wv = (const float*)d_in[8];  const float* bv = (const float*)d_in[9];
    const float* We = (const float*)d_in[10];
    const float* Ws = (const float*)d_in[11]; const float* bs = (const float*)d_in[12];
    const float* bng = (const float*)d_in[13]; const float* bnb = (const float*)d_in[14];
    const float* bnm = (const float*)d_in[15]; const float* bnv = (const float*)d_in[16];
    const float* fc1_w = (const float*)d_in[17]; const float* fc1_b = (const float*)d_in[18];
    const float* fc2_w = (const float*)d_in[19]; const float* fc2_b = (const float*)d_in[20];
    float* out = (float*)d_out;

    char* wp = (char*)d_ws;
    auto alloc = [&](size_t b) { void* p = (void*)wp; wp += (b + 255) & ~(size_t)255; return p; };
    float* xA      = (float*)alloc((size_t)N_NODES * HC * 4);
    float* xB      = (float*)alloc((size_t)N_NODES * HC * 4);
    unsigned short* Qb   = (unsigned short*)alloc((size_t)N_NODES * HC * 2);   // bf16
    unsigned short* Sb   = (unsigned short*)alloc((size_t)N_NODES * HC * 2);   // bf16
    unsigned char*  KV   = (unsigned char*)alloc((size_t)N_NODES * 2 * HC);    // fp8 e4m3, 128B/node
    unsigned short* qweb = (unsigned short*)alloc((size_t)N_NODES * HC * 2);   // bf16
    int*   deg     = (int*)alloc((size_t)N_NODES * 4);
    int*   row_ptr = (int*)alloc((size_t)(N_NODES + 1) * 4);
    int*   nxt     = (int*)alloc((size_t)N_NODES * 4);
    int*   bsum    = (int*)alloc((size_t)256 * 4);
    int*   src_s   = (int*)alloc((size_t)N_EDGES * 4);
    unsigned short* ea_s = (unsigned short*)alloc((size_t)N_EDGES * EDIM * 2); // bf16 CSR-ordered, 32B/edge

    (void)hipMemsetAsync(deg, 0, (size_t)N_NODES * 4, stream);

    count_deg<<<(N_EDGES + 255) / 256, 256, 0, stream>>>(ei, deg);
    scan1<<<SCAN_NBLK, 256, 0, stream>>>(deg, bsum);
    scan3<<<SCAN_NBLK, 256, 0, stream>>>(deg, bsum, row_ptr, nxt);
    scatter_edges<<<SCAT_BLOCKS, 256, 0, stream>>>(ei, edge_attr, nxt, src_s, ea_s);

    const float* xin = x;
    float* bufs[2] = {xA, xB};
    for (int l = 0; l < 3; l++) {
        float* xout = bufs[l & 1];
        qkvs_kernel<<<(N_NODES + QKVS_NODES - 1) / QKVS_NODES, 256, 0, stream>>>(
            xin, Wq + l * HC * HC, bq + l * HC, Wk + l * HC * HC, bk + l * HC,
            Wv + l * HC * HC, bv + l * HC, Ws + l * HC * HC, bs + l * HC,
            We + l * EDIM * HC, Qb, KV, Sb, qweb);
        attn_kernel<<<N_NODES / 8, 256, 0, stream>>>(
            Qb, qweb, KV, Sb, row_ptr, src_s, ea_s, We + l * EDIM * HC,
            bng + l * HC, bnb + l * HC, bnm + l * HC, bnv + l * HC, xout);
        xin = xout;
    }
    pool_head<<<NGRAPH / 4, 256, 0, stream>>>(xin, batch, fc1_w, fc1_b, fc2_w, fc2_b, out);
}

// Round 16
// 446.481 us; speedup vs baseline: 1.0414x; 1.0414x over previous
//
#include <hip/hip_runtime.h>
#include <math.h>

#define N_NODES 50000
#define N_EDGES 800000
#define HC 64
#define HID 16
#define EDIM 16
#define NGRAPH 2000
#define BN_EPS 1e-5f
#define QKVS_NODES 32
#define XSP 68   // xs row stride (floats): 68%4==0 (16B align), 68%32==4 -> 4 consecutive rows hit disjoint bank quads
#define SCAN_NBLK ((N_NODES + 255) / 256)   // 196
#define SCAT_BLOCKS 1024                    // multiple of 8 (XCD classes)
#define NODES_PER_CLS (N_NODES / 8)         // 6250

// ---- fp8 e4m3 (OCP) helpers: HW cvt on gfx950 ----
typedef __attribute__((ext_vector_type(2))) float v2f;
__device__ inline float4 fp8x4_to_f4(unsigned w) {
    v2f lo = __builtin_amdgcn_cvt_pk_f32_fp8((int)w, false);
    v2f hi = __builtin_amdgcn_cvt_pk_f32_fp8((int)w, true);
    return make_float4(lo[0], lo[1], hi[0], hi[1]);
}
__device__ inline unsigned char f2fp8(float f) {
    int r = __builtin_amdgcn_cvt_pk_fp8_f32(f, f, 0, false);
    return (unsigned char)(r & 0xff);
}
// ---- bf16 helpers: RNE pack, shift-expand ----
__device__ inline unsigned short f2bf(float f) {
    union { float f; unsigned u; } v; v.f = f;
    unsigned r = v.u + 0x7fffu + ((v.u >> 16) & 1u);
    return (unsigned short)(r >> 16);
}
__device__ inline float4 bf4_to_f4(uint2 r) {
    float4 o;
    o.x = __uint_as_float(r.x << 16);
    o.y = __uint_as_float(r.x & 0xffff0000u);
    o.z = __uint_as_float(r.y << 16);
    o.w = __uint_as_float(r.y & 0xffff0000u);
    return o;
}

// ---------- CSR build ----------
__global__ void count_deg(const int* __restrict__ ei, int* __restrict__ deg) {
    int e = blockIdx.x * blockDim.x + threadIdx.x;
    if (e < N_EDGES) atomicAdd(&deg[ei[N_EDGES + e]], 1);
}

__global__ __launch_bounds__(256) void scan1(const int* __restrict__ deg, int* __restrict__ bsum) {
    __shared__ int s[256];
    int tid = threadIdx.x;
    int i = blockIdx.x * 256 + tid;
    s[tid] = (i < N_NODES) ? deg[i] : 0;
    __syncthreads();
    for (int d = 128; d > 0; d >>= 1) {
        if (tid < d) s[tid] += s[tid + d];
        __syncthreads();
    }
    if (tid == 0) bsum[blockIdx.x] = s[0];
}

// scan3 folds scan2: every block redundantly prefix-scans the 196 block sums
// in LDS to derive its own exclusive block offset — one fewer dispatch.
__global__ __launch_bounds__(256) void scan3(const int* __restrict__ deg, const int* __restrict__ bsum,
                                             int* __restrict__ row_ptr, int* __restrict__ nxt) {
    __shared__ int s[256];
    __shared__ int boff_s;
    int tid = threadIdx.x;
    int v2 = (tid < SCAN_NBLK) ? bsum[tid] : 0;
    s[tid] = v2;
    __syncthreads();
    for (int d = 1; d < 256; d <<= 1) {
        int t = (tid >= d) ? s[tid - d] : 0;
        __syncthreads();
        s[tid] += t;
        __syncthreads();
    }
    if (tid == (int)blockIdx.x) boff_s = s[tid] - v2;   // exclusive prefix for this block
    __syncthreads();
    int i = blockIdx.x * 256 + tid;
    int v = (i < N_NODES) ? deg[i] : 0;
    s[tid] = v;
    __syncthreads();
    for (int d = 1; d < 256; d <<= 1) {
        int t = (tid >= d) ? s[tid - d] : 0;
        __syncthreads();
        s[tid] += t;
        __syncthreads();
    }
    int excl = s[tid] - v + boff_s;
    if (i < N_NODES) { row_ptr[i] = excl; nxt[i] = excl; }
    if (i == 0) row_ptr[N_NODES] = N_EDGES;
}

// XCD-class-partitioned scatter (R11): blocks of class (bid&7) own dst range
// [cls*6250,(cls+1)*6250) so each se_s line is written by ONE XCD's L2.
__global__ __launch_bounds__(256) void scatter_edges(const int* __restrict__ ei,
                                                     int* __restrict__ next_ptr,
                                                     int2* __restrict__ se_s) {
    int cls = blockIdx.x & 7;
    int nodeLo = cls * NODES_PER_CLS;
    int nodeHi = nodeLo + NODES_PER_CLS;
    int stride = (SCAT_BLOCKS >> 3) * 256;
    int e = (blockIdx.x >> 3) * 256 + threadIdx.x;
    for (; e < N_EDGES; e += stride) {
        int d = __builtin_nontemporal_load(ei + N_EDGES + e);
        if (d >= nodeLo && d < nodeHi) {
            int s = __builtin_nontemporal_load(ei + e);
            int p = atomicAdd(&next_ptr[d], 1);
            se_s[p] = make_int2(s, e);
        }
    }
}

// ---------- fused Q/K/V/Skip GEMM + qWe phase (R7 tiling) ----------
// Outputs: K/V fp8 (128B/node row, split K|V), Q/S/qWe bf16.
__global__ __launch_bounds__(256) void qkvs_kernel(
    const float* __restrict__ x,
    const float* __restrict__ Wq, const float* __restrict__ bq,
    const float* __restrict__ Wk, const float* __restrict__ bk,
    const float* __restrict__ Wv, const float* __restrict__ bv,
    const float* __restrict__ Ws, const float* __restrict__ bs,
    const float* __restrict__ We,
    unsigned short* __restrict__ Qo, unsigned char* __restrict__ KVo,
    unsigned short* __restrict__ So, unsigned short* __restrict__ qwe_buf) {
    __shared__ float xs[QKVS_NODES][XSP];
    int tid = threadIdx.x;
    int n0 = blockIdx.x * QKVS_NODES;
    for (int c = tid; c < QKVS_NODES * HC / 4; c += 256) {
        int row = c >> 4, col4 = c & 15;
        int n = n0 + row;
        float4 v = (n < N_NODES) ? ((const float4*)(x + (size_t)n * HC))[col4]
                                 : make_float4(0.f, 0.f, 0.f, 0.f);
        *(float4*)&xs[row][col4 * 4] = v;
    }
    __syncthreads();
    int sel = tid >> 6;
    int t = tid & 63;
    int j4 = (t & 15) * 4;        // column base (0,4,...,60)
    int ng = t >> 4;              // node sub-lane 0..3; thread's nodes: ng + 4*i
    const float* W; const float* B;
    if (sel == 0)      { W = Wq; B = bq; }
    else if (sel == 1) { W = Wk; B = bk; }
    else if (sel == 2) { W = Wv; B = bv; }
    else               { W = Ws; B = bs; }
    float4 b4 = *(const float4*)(B + j4);
    float acc[8][4];
#pragma unroll
    for (int n = 0; n < 8; n++) {
        acc[n][0] = b4.x; acc[n][1] = b4.y; acc[n][2] = b4.z; acc[n][3] = b4.w;
    }
    for (int i4 = 0; i4 < HC / 4; i4++) {
        float4 w0 = *(const float4*)(W + (i4 * 4 + 0) * HC + j4);
        float4 w1 = *(const float4*)(W + (i4 * 4 + 1) * HC + j4);
        float4 w2 = *(const float4*)(W + (i4 * 4 + 2) * HC + j4);
        float4 w3 = *(const float4*)(W + (i4 * 4 + 3) * HC + j4);
#pragma unroll
        for (int n = 0; n < 8; n++) {
            float4 xv = *(const float4*)&xs[ng + 4 * n][i4 * 4];
            acc[n][0] = fmaf(xv.x, w0.x, acc[n][0]);
            acc[n][0] = fmaf(xv.y, w1.x, acc[n][0]);
            acc[n][0] = fmaf(xv.z, w2.x, acc[n][0]);
            acc[n][0] = fmaf(xv.w, w3.x, acc[n][0]);
            acc[n][1] = fmaf(xv.x, w0.y, acc[n][1]);
            acc[n][1] = fmaf(xv.y, w1.y, acc[n][1]);
            acc[n][1] = fmaf(xv.z, w2.y, acc[n][1]);
            acc[n][1] = fmaf(xv.w, w3.y, acc[n][1]);
            acc[n][2] = fmaf(xv.x, w0.z, acc[n][2]);
            acc[n][2] = fmaf(xv.y, w1.z, acc[n][2]);
            acc[n][2] = fmaf(xv.z, w2.z, acc[n][2]);
            acc[n][2] = fmaf(xv.w, w3.z, acc[n][2]);
            acc[n][3] = fmaf(xv.x, w0.w, acc[n][3]);
            acc[n][3] = fmaf(xv.y, w1.w, acc[n][3]);
            acc[n][3] = fmaf(xv.z, w2.w, acc[n][3]);
            acc[n][3] = fmaf(xv.w, w3.w, acc[n][3]);
        }
    }
    if (sel == 0 || sel == 3) {
        unsigned short* Out = (sel == 0) ? Qo : So;
#pragma unroll
        for (int n = 0; n < 8; n++) {
            int node = n0 + ng + 4 * n;
            if (node < N_NODES) {
                ushort4 pk;
                pk.x = f2bf(acc[n][0]); pk.y = f2bf(acc[n][1]);
                pk.z = f2bf(acc[n][2]); pk.w = f2bf(acc[n][3]);
                *(ushort4*)(Out + (size_t)node * HC + j4) = pk;
            }
        }
    } else {
        int off = (sel == 1) ? 0 : HC;
#pragma unroll
        for (int n = 0; n < 8; n++) {
            int node = n0 + ng + 4 * n;
            if (node < N_NODES) {
                uchar4 pk;
                pk.x = f2fp8(acc[n][0]); pk.y = f2fp8(acc[n][1]);
                pk.z = f2fp8(acc[n][2]); pk.w = f2fp8(acc[n][3]);
                *(uchar4*)(KVo + (size_t)node * 2 * HC + off + j4) = pk;
            }
        }
    }

    // ---- phase 2: qWe[node][h*16+jj] = sum_d Q[node][h*16+d] * We[jj][h*16+d] ----
    __syncthreads();                 // xs no longer needed for x
    if (sel == 0) {
#pragma unroll
        for (int n = 0; n < 8; n++)  // Q tile (fp32) -> LDS
            *(float4*)&xs[ng + 4 * n][j4] =
                make_float4(acc[n][0], acc[n][1], acc[n][2], acc[n][3]);
    }
    __syncthreads();
    {
        int j = tid & 63;
        int h2 = j >> 4, jj = j & 15;
        float4 wv0 = *(const float4*)(We + jj * HC + h2 * 16 + 0);
        float4 wv1 = *(const float4*)(We + jj * HC + h2 * 16 + 4);
        float4 wv2 = *(const float4*)(We + jj * HC + h2 * 16 + 8);
        float4 wv3 = *(const float4*)(We + jj * HC + h2 * 16 + 12);
#pragma unroll
        for (int n = 0; n < 8; n++) {
            int nn = sel * 8 + n;
            float4 q0 = *(const float4*)&xs[nn][h2 * 16 + 0];
            float4 q1 = *(const float4*)&xs[nn][h2 * 16 + 4];
            float4 q2 = *(const float4*)&xs[nn][h2 * 16 + 8];
            float4 q3 = *(const float4*)&xs[nn][h2 * 16 + 12];
            float s = q0.x * wv0.x + q0.y * wv0.y + q0.z * wv0.z + q0.w * wv0.w
                    + q1.x * wv1.x + q1.y * wv1.y + q1.z * wv1.z + q1.w * wv1.w
                    + q2.x * wv2.x + q2.y * wv2.y + q2.z * wv2.z + q2.w * wv2.w
                    + q3.x * wv3.x + q3.y * wv3.y + q3.z * wv3.z + q3.w * wv3.w;
            int node = n0 + nn;
            if (node < N_NODES) qwe_buf[(size_t)node * HC + j] = f2bf(s);
        }
    }
}

// ---------- attention + skip + BN + ReLU (fp8 KV, bf16 Q/Qwe/S, plain-exp softmax) ----------
__global__ __launch_bounds__(256) void attn_kernel(
    const unsigned short* __restrict__ Qf, const unsigned short* __restrict__ Qwe,
    const unsigned char* __restrict__ KV, const unsigned short* __restrict__ Sf,
    const int* __restrict__ row_ptr, const int2* __restrict__ se_s,
    const float* __restrict__ edge_attr, const float* __restrict__ We,
    const float* __restrict__ bng, const float* __restrict__ bnb,
    const float* __restrict__ bnm, const float* __restrict__ bnv,
    float* __restrict__ x_out) {
    __shared__ float we_s[EDIM * HC];  // 4 KB
    int tid = threadIdx.x;
    for (int c = tid; c < EDIM * HC / 4; c += 256)
        ((float4*)we_s)[c] = ((const float4*)We)[c];
    __syncthreads();

    int lane = tid & 63;
    int wave = tid >> 6;
    int half = lane >> 5;                       // which node of the wave's pair
    int node = blockIdx.x * 8 + wave * 2 + half;  // 6250 blocks * 8 = 50000 exactly
    int sub = (lane >> 4) & 1;                  // 2 edge-streams per node
    int pos = lane & 15;
    int h = pos >> 2;
    int eaIdx = pos & 3;
    int rbeg = row_ptr[node], rend = row_ptr[node + 1];

    float4 q4 = bf4_to_f4(((const uint2*)(Qf + (size_t)node * HC))[pos]);
    float4 qwe = bf4_to_f4(((const uint2*)(Qwe + (size_t)node * HC))[pos]);  // qWe[h][jbase..+3]

    float den = 0.f;
    float4 acc = make_float4(0.f, 0.f, 0.f, 0.f);   // sum p * v
    float4 aea = make_float4(0.f, 0.f, 0.f, 0.f);   // sum p * ea

    auto proc = [&](float4 k4, float4 ea4) -> float {
        float dot = q4.x * k4.x + q4.y * k4.y + q4.z * k4.z + q4.w * k4.w
                  + qwe.x * ea4.x + qwe.y * ea4.y + qwe.z * ea4.z + qwe.w * ea4.w;
        dot += __shfl_xor(dot, 1);
        dot += __shfl_xor(dot, 2);
        float p = __expf(dot * 0.25f);
        den += p;
        return p;
    };
    auto accum = [&](float p, const float4& v, const float4& ea) {
        acc.x = fmaf(p, v.x, acc.x); acc.y = fmaf(p, v.y, acc.y);
        acc.z = fmaf(p, v.z, acc.z); acc.w = fmaf(p, v.w, acc.w);
        aea.x = fmaf(p, ea.x, aea.x); aea.y = fmaf(p, ea.y, aea.y);
        aea.z = fmaf(p, ea.z, aea.z); aea.w = fmaf(p, ea.w, aea.w);
    };

    int j = rbeg + sub;
    for (; j + 2 < rend; j += 4) {
        int2 se0 = se_s[j];
        int2 se1 = se_s[j + 2];
        const unsigned int* kv0 = (const unsigned int*)(KV + (size_t)se0.x * 2 * HC);
        const unsigned int* kv1 = (const unsigned int*)(KV + (size_t)se1.x * 2 * HC);
        unsigned int k0w = kv0[pos], v0w = kv0[16 + pos];
        unsigned int k1w = kv1[pos], v1w = kv1[16 + pos];
        float4 ea0 = ((const float4*)(edge_attr + (size_t)se0.y * EDIM))[eaIdx];
        float4 ea1 = ((const float4*)(edge_attr + (size_t)se1.y * EDIM))[eaIdx];
        float4 k0 = fp8x4_to_f4(k0w), v0 = fp8x4_to_f4(v0w);
        float4 k1 = fp8x4_to_f4(k1w), v1 = fp8x4_to_f4(v1w);
        float p0 = proc(k0, ea0);
        accum(p0, v0, ea0);
        float p1 = proc(k1, ea1);
        accum(p1, v1, ea1);
    }
    if (j < rend) {
        int2 se0 = se_s[j];
        const unsigned int* kv0 = (const unsigned int*)(KV + (size_t)se0.x * 2 * HC);
        unsigned int k0w = kv0[pos], v0w = kv0[16 + pos];
        float4 ea0 = ((const float4*)(edge_attr + (size_t)se0.y * EDIM))[eaIdx];
        float4 k0 = fp8x4_to_f4(k0w), v0 = fp8x4_to_f4(v0w);
        float p0 = proc(k0, ea0);
        accum(p0, v0, ea0);
    }

    // merge the 2 sub-stream partial sums (within the 32-lane half) — plain adds
    {
        den += __shfl_xor(den, 16);
        acc.x += __shfl_xor(acc.x, 16); acc.y += __shfl_xor(acc.y, 16);
        acc.z += __shfl_xor(acc.z, 16); acc.w += __shfl_xor(acc.w, 16);
        aea.x += __shfl_xor(aea.x, 16); aea.y += __shfl_xor(aea.y, 16);
        aea.z += __shfl_xor(aea.z, 16); aea.w += __shfl_xor(aea.w, 16);
    }

    // epilogue: e_contrib[pos*4+c] = sum_j aggEA[h][j] * We[j][pos*4+c]
    float4 e4 = make_float4(0.f, 0.f, 0.f, 0.f);
#pragma unroll
    for (int jg = 0; jg < 4; jg++) {
        int sl = (lane & 32) | (h * 4 + jg);  // lane in this half holding aggEA[h][jg*4..+3]
        float a0 = __shfl(aea.x, sl), a1 = __shfl(aea.y, sl);
        float a2 = __shfl(aea.z, sl), a3 = __shfl(aea.w, sl);
        float4 w0 = *(const float4*)(we_s + (jg * 4 + 0) * HC + pos * 4);
        float4 w1 = *(const float4*)(we_s + (jg * 4 + 1) * HC + pos * 4);
        float4 w2 = *(const float4*)(we_s + (jg * 4 + 2) * HC + pos * 4);
        float4 w3 = *(const float4*)(we_s + (jg * 4 + 3) * HC + pos * 4);
        e4.x += a0 * w0.x + a1 * w1.x + a2 * w2.x + a3 * w3.x;
        e4.y += a0 * w0.y + a1 * w1.y + a2 * w2.y + a3 * w3.y;
        e4.z += a0 * w0.z + a1 * w1.z + a2 * w2.z + a3 * w3.z;
        e4.w += a0 * w0.w + a1 * w1.w + a2 * w2.w + a3 * w3.w;
    }

    float inv = (rend > rbeg) ? 1.f / den : 0.f;
    float4 sk = bf4_to_f4(((const uint2*)(Sf + (size_t)node * HC))[pos]);
    float4 o = make_float4((acc.x + e4.x) * inv + sk.x, (acc.y + e4.y) * inv + sk.y,
                           (acc.z + e4.z) * inv + sk.z, (acc.w + e4.w) * inv + sk.w);
    float4 g4 = ((const float4*)bng)[pos];
    float4 b4 = ((const float4*)bnb)[pos];
    float4 m4 = ((const float4*)bnm)[pos];
    float4 vv4 = ((const float4*)bnv)[pos];
    o.x = fmaxf((o.x - m4.x) * rsqrtf(vv4.x + BN_EPS) * g4.x + b4.x, 0.f);
    o.y = fmaxf((o.y - m4.y) * rsqrtf(vv4.y + BN_EPS) * g4.y + b4.y, 0.f);
    o.z = fmaxf((o.z - m4.z) * rsqrtf(vv4.z + BN_EPS) * g4.z + b4.z, 0.f);
    o.w = fmaxf((o.w - m4.w) * rsqrtf(vv4.w + BN_EPS) * g4.w + b4.w, 0.f);
    if (sub == 0) ((float4*)(x_out + (size_t)node * HC))[pos] = o;
}

// ---------- fused mean-pool + MLP head: one wave per graph ----------
__global__ __launch_bounds__(256) void pool_head(
    const float* __restrict__ x, const int* __restrict__ batch,
    const float* __restrict__ fc1_w, const float* __restrict__ fc1_b,
    const float* __restrict__ fc2_w, const float* __restrict__ fc2_b,
    float* __restrict__ out) {
    __shared__ float ps[4][HC];
    int q = threadIdx.x >> 6;
    int lane = threadIdx.x & 63;
    int g = blockIdx.x * 4 + q;           // 500 * 4 = 2000 exactly
    int lo = 0, hi = N_NODES;
    while (lo < hi) { int mid = (lo + hi) >> 1; if (batch[mid] < g) lo = mid + 1; else hi = mid; }
    int beg = lo;
    lo = 0; hi = N_NODES;
    while (lo < hi) { int mid = (lo + hi) >> 1; if (batch[mid] < g + 1) lo = mid + 1; else hi = mid; }
    int end = lo;
    float s = 0.f;
    for (int i = beg; i < end; i++) s += x[(size_t)i * HC + lane];  // coalesced
    float inv = (end > beg) ? 1.f / (float)(end - beg) : 1.f;
    ps[q][lane] = s * inv;
    __syncthreads();
    float o = 0.f;
    if (lane < HID) {
        float a = fc1_b[lane];
#pragma unroll
        for (int i = 0; i < HC; i++) a = fmaf(ps[q][i], fc1_w[i * HID + lane], a);
        o = fmaxf(a, 0.f) * fc2_w[lane];
    }
    o += __shfl_xor(o, 1);
    o += __shfl_xor(o, 2);
    o += __shfl_xor(o, 4);
    o += __shfl_xor(o, 8);
    if (lane == 0) out[g] = o + fc2_b[0];
}

extern "C" void kernel_launch(void* const* d_in, const int* in_sizes, int n_in,
                              void* d_out, int out_size, void* d_ws, size_t ws_size,
                              hipStream_t stream) {
    const float* x         = (const float*)d_in[0];
    const int*   ei        = (const int*)d_in[1];
    const float* edge_attr = (const float*)d_in[2];
    const int*   batch     = (const int*)d_in[3];
    const float* Wq = (const float*)d_in[4];  const float* bq = (const float*)d_in[5];
    const float* Wk = (const float*)d_in[6];  const float* bk = (const float*)d_in[7];
    const float* Wv = (const float*)d_in[8];  const float* bv = (const float*)d_in[9];
    const float* We = (const float*)d_in[10];
    const float* Ws = (const float*)d_in[11]; const float* bs = (const float*)d_in[12];
    const float* bng = (const float*)d_in[13]; const float* bnb = (const float*)d_in[14];
    const float* bnm = (const float*)d_in[15]; const float* bnv = (const float*)d_in[16];
    const float* fc1_w = (const float*)d_in[17]; const float* fc1_b = (const float*)d_in[18];
    const float* fc2_w = (const float*)d_in[19]; const float* fc2_b = (const float*)d_in[20];
    float* out = (float*)d_out;

    char* wp = (char*)d_ws;
    auto alloc = [&](size_t b) { void* p = (void*)wp; wp += (b + 255) & ~(size_t)255; return p; };
    float* xA      = (float*)alloc((size_t)N_NODES * HC * 4);
    float* xB      = (float*)alloc((size_t)N_NODES * HC * 4);
    unsigned short* Qb   = (unsigned short*)alloc((size_t)N_NODES * HC * 2);   // bf16
    unsigned short* Sb   = (unsigned short*)alloc((size_t)N_NODES * HC * 2);   // bf16
    unsigned char*  KV   = (unsigned char*)alloc((size_t)N_NODES * 2 * HC);    // fp8 e4m3, 128B/node
    unsigned short* qweb = (unsigned short*)alloc((size_t)N_NODES * HC * 2);   // bf16
    int*   deg     = (int*)alloc((size_t)N_NODES * 4);
    int*   row_ptr = (int*)alloc((size_t)(N_NODES + 1) * 4);
    int*   nxt     = (int*)alloc((size_t)N_NODES * 4);
    int*   bsum    = (int*)alloc((size_t)256 * 4);
    int2*  se_s    = (int2*)alloc((size_t)N_EDGES * 8);

    (void)hipMemsetAsync(deg, 0, (size_t)N_NODES * 4, stream);

    count_deg<<<(N_EDGES + 255) / 256, 256, 0, stream>>>(ei, deg);
    scan1<<<SCAN_NBLK, 256, 0, stream>>>(deg, bsum);
    scan3<<<SCAN_NBLK, 256, 0, stream>>>(deg, bsum, row_ptr, nxt);
    scatter_edges<<<SCAT_BLOCKS, 256, 0, stream>>>(ei, nxt, se_s);

    const float* xin = x;
    float* bufs[2] = {xA, xB};
    for (int l = 0; l < 3; l++) {
        float* xout = bufs[l & 1];
        qkvs_kernel<<<(N_NODES + QKVS_NODES - 1) / QKVS_NODES, 256, 0, stream>>>(
            xin, Wq + l * HC * HC, bq + l * HC, Wk + l * HC * HC, bk + l * HC,
            Wv + l * HC * HC, bv + l * HC, Ws + l * HC * HC, bs + l * HC,
            We + l * EDIM * HC, Qb, KV, Sb, qweb);
        attn_kernel<<<N_NODES / 8, 256, 0, stream>>>(
            Qb, qweb, KV, Sb, row_ptr, se_s, edge_attr, We + l * EDIM * HC,
            bng + l * HC, bnb + l * HC, bnm + l * HC, bnv + l * HC, xout);
        xin = xout;
    }
    pool_head<<<NGRAPH / 4, 256, 0, stream>>>(xin, batch, fc1_w, fc1_b, fc2_w, fc2_b, out);
}